// Round 6
// baseline (196.726 us; speedup 1.0000x reference)
//
#include <hip/hip_runtime.h>
#include <math.h>

#define NSEQ   4096
#define DMODEL 640
#define NHEAD  8
#define DHEAD  64
#define INNER  512   // NHEAD*DHEAD
#define KVSPLIT 4

typedef _Float16 f16;
typedef _Float16 f16x8 __attribute__((ext_vector_type(8)));
typedef _Float16 f16x4 __attribute__((ext_vector_type(4)));
typedef float    f32x4 __attribute__((ext_vector_type(4)));

#define MFMA16(a, b, c) __builtin_amdgcn_mfma_f32_16x16x32_f16((a), (b), (c), 0, 0, 0)

// softmax scale 1/8 folded with log2(e): softmax runs in exp2 domain
#define QSCALE 0.18033688011112042f

// global -> LDS direct copy, 16B/lane, wave-uniform LDS base.
__device__ __forceinline__ void gl16(const f16* g, f16* l) {
    __builtin_amdgcn_global_load_lds(
        (const __attribute__((address_space(1))) unsigned int*)g,
        (__attribute__((address_space(3))) unsigned int*)l, 16, 0, 0);
}

// ---------------------------------------------------------------------------
// Prep: x (f32) -> xh (f16), 8 elems/thread
// ---------------------------------------------------------------------------
__global__ __launch_bounds__(256) void cvt_x(const float* __restrict__ x,
                                             f16* __restrict__ xh) {
    int i = (blockIdx.x * 256 + threadIdx.x) * 8;
    float4 a = *(const float4*)&x[i];
    float4 b = *(const float4*)&x[i + 4];
    f16x8 o = {(f16)a.x, (f16)a.y, (f16)a.z, (f16)a.w,
               (f16)b.x, (f16)b.y, (f16)b.z, (f16)b.w};
    *(f16x8*)&xh[i] = o;
}

// ---------------------------------------------------------------------------
// Prep: transpose+convert Wq/Wk/Wv f32 [640][512] -> f16 [512][640]
// ---------------------------------------------------------------------------
__global__ __launch_bounds__(256) void transpose_cvt3(
    const float* __restrict__ Wq, const float* __restrict__ Wk,
    const float* __restrict__ Wv,
    f16* __restrict__ WTq, f16* __restrict__ WTk, f16* __restrict__ WTv) {
    __shared__ __align__(16) f16 T[64][72];
    const float* src = blockIdx.z == 0 ? Wq : blockIdx.z == 1 ? Wk : Wv;
    f16* dst = blockIdx.z == 0 ? WTq : blockIdx.z == 1 ? WTk : WTv;
    const int R = DMODEL, C = INNER;
    const int c0 = blockIdx.x * 64, r0 = blockIdx.y * 64;
    const int t = threadIdx.x;
    {
        int r = t >> 2, cb = (t & 3) * 16;
#pragma unroll
        for (int i = 0; i < 16; i += 4) {
            float4 v = *(const float4*)&src[(size_t)(r0 + r) * C + c0 + cb + i];
            T[cb + i + 0][r] = (f16)v.x;
            T[cb + i + 1][r] = (f16)v.y;
            T[cb + i + 2][r] = (f16)v.z;
            T[cb + i + 3][r] = (f16)v.w;
        }
    }
    __syncthreads();
    {
        int c = t >> 2, rb = (t & 3) * 16;
        f16* d = dst + (size_t)(c0 + c) * R + r0 + rb;
        *(f16x8*)d = *(const f16x8*)&T[c][rb];
        *(f16x8*)(d + 8) = *(const f16x8*)&T[c][rb + 8];
    }
}

// Same for Wo f32 [512][640] -> WoT f16 [640][512]
__global__ __launch_bounds__(256) void transpose_cvt(
    const float* __restrict__ src, f16* __restrict__ dst, int R, int C) {
    __shared__ __align__(16) f16 T[64][72];
    const int c0 = blockIdx.x * 64, r0 = blockIdx.y * 64;
    const int t = threadIdx.x;
    {
        int r = t >> 2, cb = (t & 3) * 16;
#pragma unroll
        for (int i = 0; i < 16; i += 4) {
            float4 v = *(const float4*)&src[(size_t)(r0 + r) * C + c0 + cb + i];
            T[cb + i + 0][r] = (f16)v.x;
            T[cb + i + 1][r] = (f16)v.y;
            T[cb + i + 2][r] = (f16)v.z;
            T[cb + i + 3][r] = (f16)v.w;
        }
    }
    __syncthreads();
    {
        int c = t >> 2, rb = (t & 3) * 16;
        f16* d = dst + (size_t)(c0 + c) * R + r0 + rb;
        *(f16x8*)d = *(const f16x8*)&T[c][rb];
        *(f16x8*)(d + 8) = *(const f16x8*)&T[c][rb + 8];
    }
}

// ---------------------------------------------------------------------------
// QKV projection, f16 MFMA, BK=128 (two 64-col panels per barrier pair):
// 32 MFMA per staging round, 5 K-iters. LDS 32KB -> 5 blocks/CU.
// Outputs: z=0 Q (prescaled) [h][n][d], z=1 K [h][n][d], z=2 V^T [h][d][n].
// ---------------------------------------------------------------------------
__global__ __launch_bounds__(256, 4) void qkv_gemm16(
    const f16* __restrict__ xh,
    const f16* __restrict__ WTq, const f16* __restrict__ WTk,
    const f16* __restrict__ WTv,
    f16* __restrict__ q16, f16* __restrict__ k16, f16* __restrict__ vT16)
{
    __shared__ __align__(16) f16 Xs[8192];   // [panel 2][row 64][col 64] swz
    __shared__ __align__(16) f16 Ws[8192];
    f16 (*Cs)[72] = (f16(*)[72])Xs;          // epilogue overlay (9216B <= 16KB)

    const int bx = blockIdx.x;               // head / N-tile
    const int by = blockIdx.y;               // M-tile
    const int bz = blockIdx.z;               // 0=Q 1=K 2=V
    const f16* WT = (bz == 0) ? WTq : (bz == 1) ? WTk : WTv;

    const int tid = threadIdx.x;
    const int w = tid >> 6, lane = tid & 63;
    const int lr = lane & 15, lc = lane >> 4;
    const int srow8 = lane >> 3;
    const int le = 8 * ((lane & 7) ^ srow8);
    const int swz0 = 8 * (lc ^ (lr & 7));
    const int swz1 = 8 * ((lc + 4) ^ (lr & 7));
    const int m0 = by * 64, n0 = bx * 64;

    f32x4 acc[4] = {};

    for (int s = 0; s < DMODEL / 128; ++s) {
        const int k0 = s * 128;
#pragma unroll
        for (int c = 0; c < 4; ++c) {
            const int idx = w * 4 + c;       // 0..15
            const int p = idx >> 3, cb = idx & 7;
            gl16(xh + (size_t)(m0 + cb * 8 + srow8) * DMODEL + k0 + 64 * p + le,
                 &Xs[p * 4096 + cb * 512]);
            gl16(WT + (size_t)(n0 + cb * 8 + srow8) * DMODEL + k0 + 64 * p + le,
                 &Ws[p * 4096 + cb * 512]);
        }
        __syncthreads();
#pragma unroll
        for (int ks = 0; ks < 2; ++ks) {
            const f16* Xp = &Xs[ks * 4096];
            const f16* Wp = &Ws[ks * 4096];
            f16x8 a0 = *(const f16x8*)&Xp[(16 * w + lr) * 64 + swz0];
            f16x8 a1 = *(const f16x8*)&Xp[(16 * w + lr) * 64 + swz1];
#pragma unroll
            for (int nt = 0; nt < 4; ++nt) {
                f16x8 b0 = *(const f16x8*)&Wp[(nt * 16 + lr) * 64 + swz0];
                f16x8 b1 = *(const f16x8*)&Wp[(nt * 16 + lr) * 64 + swz1];
                acc[nt] = MFMA16(a1, b1, MFMA16(a0, b0, acc[nt]));
            }
        }
        __syncthreads();
    }

    const float sc = (bz == 0) ? QSCALE : 1.0f;
    if (bz < 2) {
#pragma unroll
        for (int nt = 0; nt < 4; ++nt)
#pragma unroll
            for (int r = 0; r < 4; ++r)
                Cs[16 * w + lc * 4 + r][nt * 16 + lr] = (f16)(acc[nt][r] * sc);
    } else {
#pragma unroll
        for (int nt = 0; nt < 4; ++nt)
#pragma unroll
            for (int r = 0; r < 4; ++r)
                Cs[nt * 16 + lr][16 * w + lc * 4 + r] = (f16)acc[nt][r];
    }
    __syncthreads();
    {
        const int rr = tid >> 2, cb = (tid & 3) * 16;
        f16x8 v0 = *(const f16x8*)&Cs[rr][cb];
        f16x8 v1 = *(const f16x8*)&Cs[rr][cb + 8];
        f16* dst;
        if (bz == 0)
            dst = q16 + ((size_t)bx * NSEQ + m0 + rr) * DHEAD + cb;
        else if (bz == 1)
            dst = k16 + ((size_t)bx * NSEQ + m0 + rr) * DHEAD + cb;
        else
            dst = vT16 + ((size_t)bx * DHEAD + rr) * NSEQ + m0 + cb;
        *(f16x8*)dst = v0;
        *(f16x8*)(dst + 8) = v1;
    }
}

// ---------------------------------------------------------------------------
// Flash attention, kv-split=4. Block = (qtile 64, head, quarter); 4 waves.
// LDS 16KB (P overwrites K after QK^T; one extra barrier makes it safe)
// -> 8 blocks/CU = 32 waves/CU. Swapped QK^T, exp2 domain, exact defer-max.
// XCD remap: head == XCD (K/V L2-resident). Emits per-split normalized O
// (f16) + (m,l); combined in out_gemm.
// ---------------------------------------------------------------------------
__global__ __launch_bounds__(256, 8) void attn_fwd(
    const f16* __restrict__ q16, const f16* __restrict__ k16,
    const f16* __restrict__ vT16, f16* __restrict__ Opart,
    float* __restrict__ Ml)
{
    __shared__ __align__(16) f16 Ks[4096];   // [kv 64][d 64] swz; P after QK^T
    __shared__ __align__(16) f16 Vt[4096];   // [d 64][kv 64] swz

    // XCD-aware remap: lin == dispatch index; h = lin & 7 -> one head per XCD
    const int lin = blockIdx.x + 64 * blockIdx.y + 512 * blockIdx.z;
    const int h  = lin & 7;
    const int qb = (lin >> 3) & 63;
    const int sp = lin >> 9;                  // kv quarter: 0..3

    const int tid = threadIdx.x;
    const int w = tid >> 6, lane = tid & 63;
    const int lr = lane & 15, lc = lane >> 4;
    const int srow8 = lane >> 3;
    const int le = 8 * ((lane & 7) ^ srow8);
    const int swz0 = 8 * (lc ^ (lr & 7));
    const int swz1 = 8 * ((lc + 4) ^ (lr & 7));

    const f16* kp = k16 + ((size_t)h * NSEQ + sp * (NSEQ / KVSPLIT)) * DHEAD;
    const f16* vp = vT16 + (size_t)h * DHEAD * NSEQ + sp * (NSEQ / KVSPLIT);

    // Q fragments (persistent, prescaled by 0.125*log2e)
    const f16* qp = q16 + ((size_t)h * NSEQ + qb * 64 + 16 * w + lr) * DHEAD;
    const f16x8 qf0 = *(const f16x8*)&qp[lc * 8];
    const f16x8 qf1 = *(const f16x8*)&qp[32 + lc * 8];

    float m_run = -INFINITY, l_run = 0.f;
    f32x4 o[4] = {};

    for (int kt = 0; kt < NSEQ / KVSPLIT / 64; ++kt) {
        // ---- stage K tile and V^T tile (wave w: chunks 2w, 2w+1)
#pragma unroll
        for (int c = 0; c < 2; ++c) {
            const int cc = 2 * w + c;
            gl16(kp + (size_t)(kt * 64 + cc * 8 + srow8) * DHEAD + le,
                 &Ks[cc * 512]);
            gl16(vp + (size_t)(cc * 8 + srow8) * NSEQ + kt * 64 + le,
                 &Vt[cc * 512]);
        }
        __syncthreads();                       // (1) staged

        // ---- S^T = K Q^T: lane holds S[q = lr][kv = 16t + 4lc + r]
        f32x4 sv[4];
        const f32x4 z4 = {0.f, 0.f, 0.f, 0.f};
#pragma unroll
        for (int t = 0; t < 4; ++t) {
            f16x8 ka = *(const f16x8*)&Ks[(t * 16 + lr) * 64 + swz0];
            f16x8 kb = *(const f16x8*)&Ks[(t * 16 + lr) * 64 + swz1];
            sv[t] = MFMA16(kb, qf1, MFMA16(ka, qf0, z4));
        }

        // ---- lane-local online softmax (exp2 domain), exact defer-max
        float pm = sv[0][0];
#pragma unroll
        for (int t = 0; t < 4; ++t)
#pragma unroll
            for (int r = 0; r < 4; ++r) pm = fmaxf(pm, sv[t][r]);
        pm = fmaxf(pm, __shfl_xor(pm, 16));
        pm = fmaxf(pm, __shfl_xor(pm, 32));
        if (__any(pm > m_run)) {
            const float mn = fmaxf(m_run, pm);
            const float al = __builtin_amdgcn_exp2f(m_run - mn);
            m_run = mn;
            l_run *= al;
#pragma unroll
            for (int dt = 0; dt < 4; ++dt) o[dt] *= al;
        }
        float p[4][4];
        float ps = 0.f;
#pragma unroll
        for (int t = 0; t < 4; ++t)
#pragma unroll
            for (int r = 0; r < 4; ++r) {
                p[t][r] = __builtin_amdgcn_exp2f(sv[t][r] - m_run);
                ps += p[t][r];
            }
        ps += __shfl_xor(ps, 16);
        ps += __shfl_xor(ps, 32);
        l_run += ps;

        __syncthreads();                       // (2) all QK^T reads of Ks done

        // ---- P -> Ks strip (wave-private rows 16w..16w+15), swizzled
#pragma unroll
        for (int t = 0; t < 4; ++t) {
            f16x4 pk = {(f16)p[t][0], (f16)p[t][1], (f16)p[t][2], (f16)p[t][3]};
            const int col = (16 * t + 4 * lc) ^ ((lr & 7) << 3);
            *(f16x4*)&Ks[(16 * w + lr) * 64 + col] = pk;
        }

        // ---- O^T += V^T P^T (P read from own strip; Vt shared, stage-only)
        f16x8 pb0 = *(const f16x8*)&Ks[(16 * w + lr) * 64 + swz0];
        f16x8 pb1 = *(const f16x8*)&Ks[(16 * w + lr) * 64 + swz1];
#pragma unroll
        for (int dt = 0; dt < 4; ++dt) {
            f16x8 va0 = *(const f16x8*)&Vt[(dt * 16 + lr) * 64 + swz0];
            f16x8 va1 = *(const f16x8*)&Vt[(dt * 16 + lr) * 64 + swz1];
            o[dt] = MFMA16(va1, pb1, MFMA16(va0, pb0, o[dt]));
        }
        __syncthreads();                       // (3) reads done, buffers free
    }

    // ---- epilogue: per-split normalized O (f16) + (m,l)
    const float linv = 1.0f / l_run;
    const size_t qg = (size_t)qb * 64 + 16 * w + lr;
    f16* ob = Opart + (((size_t)(sp * 8 + h)) * NSEQ + qg) * DHEAD;
#pragma unroll
    for (int dt = 0; dt < 4; ++dt) {
        f16x4 ov = {(f16)(o[dt][0] * linv), (f16)(o[dt][1] * linv),
                    (f16)(o[dt][2] * linv), (f16)(o[dt][3] * linv)};
        *(f16x4*)&ob[dt * 16 + 4 * lc] = ov;
    }
    if (lc == 0) {
        float2 ml = make_float2(m_run, l_run);
        *(float2*)&Ml[(((size_t)(sp * 8 + h)) * NSEQ + qg) * 2] = ml;
    }
}

// ---------------------------------------------------------------------------
// Output projection + 4-way kv-split combine. K-step s8 == head s8.
// ---------------------------------------------------------------------------
__global__ __launch_bounds__(256, 4) void out_gemm16(
    const f16* __restrict__ Opart, const float* __restrict__ Ml,
    const f16* __restrict__ WoT,
    const float* __restrict__ bias, float* __restrict__ C)
{
    __shared__ __align__(16) f16 Xs[4096];
    __shared__ __align__(16) f16 Ws[4096];

    const int bx = blockIdx.x;   // N-tile 0..9
    const int by = blockIdx.y;   // M-tile 0..63
    const int tid = threadIdx.x;
    const int w = tid >> 6, lane = tid & 63;
    const int lr = lane & 15, lc = lane >> 4;
    const int srow8 = lane >> 3;
    const int j = lane & 7;
    const int le = 8 * (j ^ srow8);
    const int swz0 = 8 * (lc ^ (lr & 7));
    const int swz1 = 8 * ((lc + 4) ^ (lr & 7));
    const int m0 = by * 64, n0 = bx * 64;

    f32x4 acc[4] = {};

    for (int s8 = 0; s8 < 8; ++s8) {         // K-step == head
        const int k0 = s8 * 64;
#pragma unroll
        for (int c = 0; c < 2; ++c) {
            const int cc = w * 2 + c;
            gl16(WoT + (size_t)(n0 + cc * 8 + srow8) * INNER + k0 + le,
                 &Ws[cc * 512]);
            // A: combine 4 normalized partials in registers
            const int row = cc * 8 + srow8;
            const size_t q = (size_t)m0 + row;
            f16x8 op[KVSPLIT];
            float mm[KVSPLIT], ll[KVSPLIT];
#pragma unroll
            for (int spp = 0; spp < KVSPLIT; ++spp) {
                op[spp] = *(const f16x8*)
                    &Opart[((size_t)(spp * 8 + s8) * NSEQ + q) * DHEAD + 8 * j];
                float2 ml = *(const float2*)
                    &Ml[((size_t)(spp * 8 + s8) * NSEQ + q) * 2];
                mm[spp] = ml.x; ll[spp] = ml.y;
            }
            float mx = fmaxf(fmaxf(mm[0], mm[1]), fmaxf(mm[2], mm[3]));
            float wt[KVSPLIT], tot = 0.f;
#pragma unroll
            for (int spp = 0; spp < KVSPLIT; ++spp) {
                wt[spp] = ll[spp] * __builtin_amdgcn_exp2f(mm[spp] - mx);
                tot += wt[spp];
            }
            const float inv = 1.0f / tot;
            f16x8 a8;
#pragma unroll
            for (int e = 0; e < 8; ++e) {
                float v = 0.f;
#pragma unroll
                for (int spp = 0; spp < KVSPLIT; ++spp)
                    v += (float)op[spp][e] * wt[spp];
                a8[e] = (f16)(v * inv);
            }
            *(f16x8*)&Xs[row * 64 + 8 * (j ^ (row & 7))] = a8;
        }
        __syncthreads();
        f16x8 a0 = *(const f16x8*)&Xs[(16 * w + lr) * 64 + swz0];
        f16x8 a1 = *(const f16x8*)&Xs[(16 * w + lr) * 64 + swz1];
#pragma unroll
        for (int nt = 0; nt < 4; ++nt) {
            f16x8 b0 = *(const f16x8*)&Ws[(nt * 16 + lr) * 64 + swz0];
            f16x8 b1 = *(const f16x8*)&Ws[(nt * 16 + lr) * 64 + swz1];
            acc[nt] = MFMA16(a1, b1, MFMA16(a0, b0, acc[nt]));
        }
        __syncthreads();
    }

#pragma unroll
    for (int nt = 0; nt < 4; ++nt) {
        const float b = bias[n0 + nt * 16 + lr];
#pragma unroll
        for (int r = 0; r < 4; ++r)
            C[(size_t)(m0 + 16 * w + lc * 4 + r) * DMODEL + n0 + nt * 16 + lr] =
                acc[nt][r] + b;
    }
}

extern "C" void kernel_launch(void* const* d_in, const int* in_sizes, int n_in,
                              void* d_out, int out_size, void* d_ws, size_t ws_size,
                              hipStream_t stream) {
    const float* x  = (const float*)d_in[0];
    const float* Wq = (const float*)d_in[1];
    const float* Wk = (const float*)d_in[2];
    const float* Wv = (const float*)d_in[3];
    const float* Wo = (const float*)d_in[4];
    const float* bo = (const float*)d_in[5];
    float* out = (float*)d_out;

    // Workspace layout (bytes). Opart overlays xh/WTq/WTk/WTv (disjoint
    // lifetimes: xh/WT die at qkv_gemm16 end; Opart born in attn_fwd).
    char* base = (char*)d_ws;
    f16*   Opart = (f16*)base;                   // 4*8*4096*64*2 = 16,777,216
    f16*   xh    = (f16*)base;                   // 5,242,880
    f16*   WTq   = xh + (size_t)NSEQ * DMODEL;
    f16*   WTk   = WTq + (size_t)INNER * DMODEL;
    f16*   WTv   = WTk + (size_t)INNER * DMODEL; // ends 7,208,960 < 16.7M
    float* Ml    = (float*)(base + 16777216);    // 4*8*4096*2*4 = 1,048,576
    f16*   WoT   = (f16*)(base + 17825792);      // 655,360
    f16*   q16   = (f16*)(base + 18481152);      // 4,194,304
    f16*   k16   = q16 + (size_t)NHEAD * NSEQ * DHEAD;
    f16*   vT16  = k16 + (size_t)NHEAD * NSEQ * DHEAD;  // ends 31,064,064 B

    cvt_x<<<NSEQ * DMODEL / (256 * 8), 256, 0, stream>>>(x, xh);
    transpose_cvt3<<<dim3(INNER / 64, DMODEL / 64, 3), 256, 0, stream>>>(
        Wq, Wk, Wv, WTq, WTk, WTv);
    transpose_cvt<<<dim3(DMODEL / 64, INNER / 64), 256, 0, stream>>>(
        Wo, WoT, INNER, DMODEL);

    qkv_gemm16<<<dim3(NHEAD, NSEQ / 64, 3), 256, 0, stream>>>(
        xh, WTq, WTk, WTv, q16, k16, vT16);
    attn_fwd<<<dim3(NSEQ / 64, NHEAD, KVSPLIT), 256, 0, stream>>>(
        q16, k16, vT16, Opart, Ml);
    out_gemm16<<<dim3(DMODEL / 64, NSEQ / 64), 256, 0, stream>>>(
        Opart, Ml, WoT, bo, out);
}

// Round 8
// 172.624 us; speedup vs baseline: 1.1396x; 1.1396x over previous
//
#include <hip/hip_runtime.h>
#include <math.h>

#define NSEQ   4096
#define DMODEL 640
#define NHEAD  8
#define DHEAD  64
#define INNER  512   // NHEAD*DHEAD
#define KVSPLIT 2

typedef _Float16 f16;
typedef _Float16 f16x8 __attribute__((ext_vector_type(8)));
typedef _Float16 f16x4 __attribute__((ext_vector_type(4)));
typedef float    f32x4 __attribute__((ext_vector_type(4)));

#define MFMA16(a, b, c) __builtin_amdgcn_mfma_f32_16x16x32_f16((a), (b), (c), 0, 0, 0)

// softmax scale 1/8 folded with log2(e): softmax runs in exp2 domain
#define QSCALE 0.18033688011112042f

// global -> LDS direct copy, 16B/lane, wave-uniform LDS base.
__device__ __forceinline__ void gl16(const f16* g, f16* l) {
    __builtin_amdgcn_global_load_lds(
        (const __attribute__((address_space(1))) unsigned int*)g,
        (__attribute__((address_space(3))) unsigned int*)l, 16, 0, 0);
}

// ---------------------------------------------------------------------------
// Prep: x (f32) -> xh (f16), 8 elems/thread
// ---------------------------------------------------------------------------
__global__ __launch_bounds__(256) void cvt_x(const float* __restrict__ x,
                                             f16* __restrict__ xh) {
    int i = (blockIdx.x * 256 + threadIdx.x) * 8;
    float4 a = *(const float4*)&x[i];
    float4 b = *(const float4*)&x[i + 4];
    f16x8 o = {(f16)a.x, (f16)a.y, (f16)a.z, (f16)a.w,
               (f16)b.x, (f16)b.y, (f16)b.z, (f16)b.w};
    *(f16x8*)&xh[i] = o;
}

// ---------------------------------------------------------------------------
// Prep: transpose+convert Wq/Wk/Wv f32 [640][512] -> f16 [512][640]
// ---------------------------------------------------------------------------
__global__ __launch_bounds__(256) void transpose_cvt3(
    const float* __restrict__ Wq, const float* __restrict__ Wk,
    const float* __restrict__ Wv,
    f16* __restrict__ WTq, f16* __restrict__ WTk, f16* __restrict__ WTv) {
    __shared__ __align__(16) f16 T[64][72];
    const float* src = blockIdx.z == 0 ? Wq : blockIdx.z == 1 ? Wk : Wv;
    f16* dst = blockIdx.z == 0 ? WTq : blockIdx.z == 1 ? WTk : WTv;
    const int R = DMODEL, C = INNER;
    const int c0 = blockIdx.x * 64, r0 = blockIdx.y * 64;
    const int t = threadIdx.x;
    {
        int r = t >> 2, cb = (t & 3) * 16;
#pragma unroll
        for (int i = 0; i < 16; i += 4) {
            float4 v = *(const float4*)&src[(size_t)(r0 + r) * C + c0 + cb + i];
            T[cb + i + 0][r] = (f16)v.x;
            T[cb + i + 1][r] = (f16)v.y;
            T[cb + i + 2][r] = (f16)v.z;
            T[cb + i + 3][r] = (f16)v.w;
        }
    }
    __syncthreads();
    {
        int c = t >> 2, rb = (t & 3) * 16;
        f16* d = dst + (size_t)(c0 + c) * R + r0 + rb;
        *(f16x8*)d = *(const f16x8*)&T[c][rb];
        *(f16x8*)(d + 8) = *(const f16x8*)&T[c][rb + 8];
    }
}

// Same for Wo f32 [512][640] -> WoT f16 [640][512]
__global__ __launch_bounds__(256) void transpose_cvt(
    const float* __restrict__ src, f16* __restrict__ dst, int R, int C) {
    __shared__ __align__(16) f16 T[64][72];
    const int c0 = blockIdx.x * 64, r0 = blockIdx.y * 64;
    const int t = threadIdx.x;
    {
        int r = t >> 2, cb = (t & 3) * 16;
#pragma unroll
        for (int i = 0; i < 16; i += 4) {
            float4 v = *(const float4*)&src[(size_t)(r0 + r) * C + c0 + cb + i];
            T[cb + i + 0][r] = (f16)v.x;
            T[cb + i + 1][r] = (f16)v.y;
            T[cb + i + 2][r] = (f16)v.z;
            T[cb + i + 3][r] = (f16)v.w;
        }
    }
    __syncthreads();
    {
        int c = t >> 2, rb = (t & 3) * 16;
        f16* d = dst + (size_t)(c0 + c) * R + r0 + rb;
        *(f16x8*)d = *(const f16x8*)&T[c][rb];
        *(f16x8*)(d + 8) = *(const f16x8*)&T[c][rb + 8];
    }
}

// ---------------------------------------------------------------------------
// QKV projection, f16 MFMA (round-5 form: BK=64, 2-barrier loop).
// Outputs: z=0 Q (prescaled) [h][n][d], z=1 K [h][n][d], z=2 V^T [h][d][n].
// ---------------------------------------------------------------------------
__global__ __launch_bounds__(256) void qkv_gemm16(
    const f16* __restrict__ xh,
    const f16* __restrict__ WTq, const f16* __restrict__ WTk,
    const f16* __restrict__ WTv,
    f16* __restrict__ q16, f16* __restrict__ k16, f16* __restrict__ vT16)
{
    __shared__ __align__(16) f16 Xs[4096];
    __shared__ __align__(16) f16 Ws[4096];
    __shared__ __align__(16) f16 Cs[64][72];

    const int bx = blockIdx.x;               // head / N-tile
    const int by = blockIdx.y;               // M-tile
    const int bz = blockIdx.z;               // 0=Q 1=K 2=V
    const f16* WT = (bz == 0) ? WTq : (bz == 1) ? WTk : WTv;

    const int tid = threadIdx.x;
    const int w = tid >> 6, lane = tid & 63;
    const int lr = lane & 15, lc = lane >> 4;
    const int srow8 = lane >> 3;
    const int le = 8 * ((lane & 7) ^ srow8);
    const int swz0 = 8 * (lc ^ (lr & 7));
    const int swz1 = 8 * ((lc + 4) ^ (lr & 7));
    const int m0 = by * 64, n0 = bx * 64;

    f32x4 acc[4] = {};

    for (int s = 0; s < DMODEL / 64; ++s) {
        const int k0 = s * 64;
#pragma unroll
        for (int c = 0; c < 2; ++c) {
            const int cc = w * 2 + c;
            gl16(xh + (size_t)(m0 + cc * 8 + srow8) * DMODEL + k0 + le,
                 &Xs[cc * 512]);
            gl16(WT + (size_t)(n0 + cc * 8 + srow8) * DMODEL + k0 + le,
                 &Ws[cc * 512]);
        }
        __syncthreads();
        f16x8 a0 = *(const f16x8*)&Xs[(16 * w + lr) * 64 + swz0];
        f16x8 a1 = *(const f16x8*)&Xs[(16 * w + lr) * 64 + swz1];
#pragma unroll
        for (int nt = 0; nt < 4; ++nt) {
            f16x8 b0 = *(const f16x8*)&Ws[(nt * 16 + lr) * 64 + swz0];
            f16x8 b1 = *(const f16x8*)&Ws[(nt * 16 + lr) * 64 + swz1];
            acc[nt] = MFMA16(a1, b1, MFMA16(a0, b0, acc[nt]));
        }
        __syncthreads();
    }

    const float sc = (bz == 0) ? QSCALE : 1.0f;
    if (bz < 2) {
#pragma unroll
        for (int nt = 0; nt < 4; ++nt)
#pragma unroll
            for (int r = 0; r < 4; ++r)
                Cs[16 * w + lc * 4 + r][nt * 16 + lr] = (f16)(acc[nt][r] * sc);
    } else {
#pragma unroll
        for (int nt = 0; nt < 4; ++nt)
#pragma unroll
            for (int r = 0; r < 4; ++r)
                Cs[nt * 16 + lr][16 * w + lc * 4 + r] = (f16)acc[nt][r];
    }
    __syncthreads();
    {
        const int rr = tid >> 2, cb = (tid & 3) * 16;
        f16x8 v0 = *(const f16x8*)&Cs[rr][cb];
        f16x8 v1 = *(const f16x8*)&Cs[rr][cb + 8];
        f16* dst;
        if (bz == 0)
            dst = q16 + ((size_t)bx * NSEQ + m0 + rr) * DHEAD + cb;
        else if (bz == 1)
            dst = k16 + ((size_t)bx * NSEQ + m0 + rr) * DHEAD + cb;
        else
            dst = vT16 + ((size_t)bx * DHEAD + rr) * NSEQ + m0 + cb;
        *(f16x8*)dst = v0;
        *(f16x8*)(dst + 8) = v1;
    }
}

// ---------------------------------------------------------------------------
// Flash attention, fragment-reuse form. Block = (qtile 128, head, half);
// 4 waves; wave owns 32 q-rows (2 groups of 16) -> each K/V fragment read
// feeds TWO MFMAs (LDS reads per FLOP ~1.8x down vs round 5), and K/V
// staging traffic halves. K/V double-buffered via global_load_lds
// (prefetch t+1 issued before compute t), ONE barrier per tile.
// LDS 48KB -> grid 512 = 2 blocks/CU (occupancy proven non-limiting in r6).
// Swapped QK^T, lane-local softmax in exp2 domain, exact defer-max.
// XCD remap: head == XCD. Emits per-split normalized O + (m,l).
// ---------------------------------------------------------------------------
__global__ __launch_bounds__(256, 2) void attn_fwd(
    const f16* __restrict__ q16, const f16* __restrict__ k16,
    const f16* __restrict__ vT16, f16* __restrict__ Opart,
    float* __restrict__ Ml)
{
    __shared__ __align__(16) f16 KsB[2][4096];   // [kv 64][d 64] swizzled
    __shared__ __align__(16) f16 VtB[2][4096];   // [d 64][kv 64] swizzled
    __shared__ __align__(16) f16 Ps[8192];       // [q 128][kv 64] swizzled

    // XCD-aware remap: 512 blocks, dispatch round-robins XCDs -> h = lin&7
    const int lin = blockIdx.x + 32 * blockIdx.y + 256 * blockIdx.z;
    const int h  = lin & 7;
    const int qb = (lin >> 3) & 31;              // q-tile of 128 rows
    const int sp = lin >> 8;                     // kv half 0/1

    const int tid = threadIdx.x;
    const int w = tid >> 6, lane = tid & 63;
    const int lr = lane & 15, lc = lane >> 4;
    const int srow8 = lane >> 3;
    const int le = 8 * ((lane & 7) ^ srow8);
    const int swz0 = 8 * (lc ^ (lr & 7));
    const int swz1 = 8 * ((lc + 4) ^ (lr & 7));

    const f16* kp = k16 + ((size_t)h * NSEQ + sp * (NSEQ / KVSPLIT)) * DHEAD;
    const f16* vp = vT16 + (size_t)h * DHEAD * NSEQ + sp * (NSEQ / KVSPLIT);

    // Q fragments: wave rows qb*128 + 32w + 16g + lr, g=0,1 (prescaled)
    f16x8 qf[2][2];
#pragma unroll
    for (int g = 0; g < 2; ++g) {
        const f16* qp = q16 +
            ((size_t)h * NSEQ + qb * 128 + 32 * w + 16 * g + lr) * DHEAD;
        qf[g][0] = *(const f16x8*)&qp[lc * 8];
        qf[g][1] = *(const f16x8*)&qp[32 + lc * 8];
    }

    float m_run[2] = {-INFINITY, -INFINITY}, l_run[2] = {0.f, 0.f};
    f32x4 o[2][4] = {};

    // stage tile 0 into buffer 0 (wave w: chunks 2w, 2w+1 of each)
#pragma unroll
    for (int c = 0; c < 2; ++c) {
        const int cc = 2 * w + c;
        gl16(kp + (size_t)(cc * 8 + srow8) * DHEAD + le, &KsB[0][cc * 512]);
        gl16(vp + (size_t)(cc * 8 + srow8) * NSEQ + le, &VtB[0][cc * 512]);
    }
    __syncthreads();

    const int NT = NSEQ / KVSPLIT / 64;          // 32
    for (int kt = 0; kt < NT; ++kt) {
        const int cur = kt & 1;
        if (kt < NT - 1) {                       // prefetch t+1 (async)
            const int nb = cur ^ 1;
#pragma unroll
            for (int c = 0; c < 2; ++c) {
                const int cc = 2 * w + c;
                gl16(kp + (size_t)((kt + 1) * 64 + cc * 8 + srow8) * DHEAD + le,
                     &KsB[nb][cc * 512]);
                gl16(vp + (size_t)(cc * 8 + srow8) * NSEQ + (kt + 1) * 64 + le,
                     &VtB[nb][cc * 512]);
            }
        }

        // ---- S^T = K Q^T: lane holds S[q = group row lr][kv = 16t+4lc+r]
        f32x4 s[2][4];
        const f32x4 z4 = {0.f, 0.f, 0.f, 0.f};
#pragma unroll
        for (int t = 0; t < 4; ++t) {
            f16x8 ka = *(const f16x8*)&KsB[cur][(t * 16 + lr) * 64 + swz0];
            f16x8 kb = *(const f16x8*)&KsB[cur][(t * 16 + lr) * 64 + swz1];
#pragma unroll
            for (int g = 0; g < 2; ++g)
                s[g][t] = MFMA16(kb, qf[g][1], MFMA16(ka, qf[g][0], z4));
        }

        // ---- lane-local online softmax (exp2 domain), exact defer-max
        float pm[2];
#pragma unroll
        for (int g = 0; g < 2; ++g) {
            float m = s[g][0][0];
#pragma unroll
            for (int t = 0; t < 4; ++t)
#pragma unroll
                for (int r = 0; r < 4; ++r) m = fmaxf(m, s[g][t][r]);
            m = fmaxf(m, __shfl_xor(m, 16));
            m = fmaxf(m, __shfl_xor(m, 32));
            pm[g] = m;
        }
        if (__any((pm[0] > m_run[0]) | (pm[1] > m_run[1]))) {
#pragma unroll
            for (int g = 0; g < 2; ++g) {
                const float mn = fmaxf(m_run[g], pm[g]);
                const float al = __builtin_amdgcn_exp2f(m_run[g] - mn);
                m_run[g] = mn;
                l_run[g] *= al;
#pragma unroll
                for (int dt = 0; dt < 4; ++dt) o[g][dt] *= al;
            }
        }
#pragma unroll
        for (int g = 0; g < 2; ++g) {
            float ps = 0.f;
#pragma unroll
            for (int t = 0; t < 4; ++t)
#pragma unroll
                for (int r = 0; r < 4; ++r) {
                    s[g][t][r] = __builtin_amdgcn_exp2f(s[g][t][r] - m_run[g]);
                    ps += s[g][t][r];
                }
            ps += __shfl_xor(ps, 16);
            ps += __shfl_xor(ps, 32);
            l_run[g] += ps;
        }

        // ---- P -> own strip (rows 32w+16g+lr), swizzled like reads
#pragma unroll
        for (int g = 0; g < 2; ++g) {
            const int row = 32 * w + 16 * g + lr;
#pragma unroll
            for (int t = 0; t < 4; ++t) {
                f16x4 pk = {(f16)s[g][t][0], (f16)s[g][t][1],
                            (f16)s[g][t][2], (f16)s[g][t][3]};
                const int col = (16 * t + 4 * lc) ^ ((lr & 7) << 3);
                *(f16x4*)&Ps[row * 64 + col] = pk;
            }
        }

        // ---- O^T += V^T P^T (V fragments reused across both q-groups)
        f16x8 pb[2][2];
#pragma unroll
        for (int g = 0; g < 2; ++g) {
            const int row = 32 * w + 16 * g + lr;
            pb[g][0] = *(const f16x8*)&Ps[row * 64 + swz0];
            pb[g][1] = *(const f16x8*)&Ps[row * 64 + swz1];
        }
#pragma unroll
        for (int dt = 0; dt < 4; ++dt) {
            f16x8 va0 = *(const f16x8*)&VtB[cur][(dt * 16 + lr) * 64 + swz0];
            f16x8 va1 = *(const f16x8*)&VtB[cur][(dt * 16 + lr) * 64 + swz1];
#pragma unroll
            for (int g = 0; g < 2; ++g)
                o[g][dt] = MFMA16(va1, pb[g][1], MFMA16(va0, pb[g][0], o[g][dt]));
        }
        __syncthreads();   // prefetch landed; all reads of buf[cur] done
    }

    // ---- epilogue: per-split normalized O (f16) + (m,l)
#pragma unroll
    for (int g = 0; g < 2; ++g) {
        const float linv = 1.0f / l_run[g];
        const size_t qg = (size_t)qb * 128 + 32 * w + 16 * g + lr;
        f16* ob = Opart + (((size_t)(sp * 8 + h)) * NSEQ + qg) * DHEAD;
#pragma unroll
        for (int dt = 0; dt < 4; ++dt) {
            f16x4 ov = {(f16)(o[g][dt][0] * linv), (f16)(o[g][dt][1] * linv),
                        (f16)(o[g][dt][2] * linv), (f16)(o[g][dt][3] * linv)};
            *(f16x4*)&ob[dt * 16 + 4 * lc] = ov;
        }
        if (lc == 0) {
            float2 ml = make_float2(m_run[g], l_run[g]);
            *(float2*)&Ml[(((size_t)(sp * 8 + h)) * NSEQ + qg) * 2] = ml;
        }
    }
}

// ---------------------------------------------------------------------------
// Output projection + 2-way kv-split combine (round-5 form). K-step == head.
// ---------------------------------------------------------------------------
__global__ __launch_bounds__(256) void out_gemm16(
    const f16* __restrict__ Opart, const float* __restrict__ Ml,
    const f16* __restrict__ WoT,
    const float* __restrict__ bias, float* __restrict__ C)
{
    __shared__ __align__(16) f16 Xs[4096];
    __shared__ __align__(16) f16 Ws[4096];

    const int bx = blockIdx.x;   // N-tile 0..9
    const int by = blockIdx.y;   // M-tile 0..63
    const int tid = threadIdx.x;
    const int w = tid >> 6, lane = tid & 63;
    const int lr = lane & 15, lc = lane >> 4;
    const int srow8 = lane >> 3;
    const int j = lane & 7;
    const int le = 8 * (j ^ srow8);
    const int swz0 = 8 * (lc ^ (lr & 7));
    const int swz1 = 8 * ((lc + 4) ^ (lr & 7));
    const int m0 = by * 64, n0 = bx * 64;

    f32x4 acc[4] = {};

    for (int s8 = 0; s8 < 8; ++s8) {         // K-step == head
        const int k0 = s8 * 64;
#pragma unroll
        for (int c = 0; c < 2; ++c) {
            const int cc = w * 2 + c;
            gl16(WoT + (size_t)(n0 + cc * 8 + srow8) * INNER + k0 + le,
                 &Ws[cc * 512]);
            // A: combine the two normalized partials in registers
            const int row = cc * 8 + srow8;
            const size_t q = (size_t)m0 + row;
            f16x8 o0 = *(const f16x8*)&Opart[((size_t)s8 * NSEQ + q) * DHEAD + 8 * j];
            f16x8 o1 = *(const f16x8*)&Opart[((size_t)(8 + s8) * NSEQ + q) * DHEAD + 8 * j];
            float2 ml0 = *(const float2*)&Ml[((size_t)s8 * NSEQ + q) * 2];
            float2 ml1 = *(const float2*)&Ml[((size_t)(8 + s8) * NSEQ + q) * 2];
            const float mx = fmaxf(ml0.x, ml1.x);
            float w0 = ml0.y * __builtin_amdgcn_exp2f(ml0.x - mx);
            float w1 = ml1.y * __builtin_amdgcn_exp2f(ml1.x - mx);
            const float inv = 1.0f / (w0 + w1);
            w0 *= inv; w1 *= inv;
            f16x8 a8;
#pragma unroll
            for (int e = 0; e < 8; ++e)
                a8[e] = (f16)((float)o0[e] * w0 + (float)o1[e] * w1);
            *(f16x8*)&Xs[row * 64 + 8 * (j ^ (row & 7))] = a8;
        }
        __syncthreads();
        f16x8 a0 = *(const f16x8*)&Xs[(16 * w + lr) * 64 + swz0];
        f16x8 a1 = *(const f16x8*)&Xs[(16 * w + lr) * 64 + swz1];
#pragma unroll
        for (int nt = 0; nt < 4; ++nt) {
            f16x8 b0 = *(const f16x8*)&Ws[(nt * 16 + lr) * 64 + swz0];
            f16x8 b1 = *(const f16x8*)&Ws[(nt * 16 + lr) * 64 + swz1];
            acc[nt] = MFMA16(a1, b1, MFMA16(a0, b0, acc[nt]));
        }
        __syncthreads();
    }

#pragma unroll
    for (int nt = 0; nt < 4; ++nt) {
        const float b = bias[n0 + nt * 16 + lr];
#pragma unroll
        for (int r = 0; r < 4; ++r)
            C[(size_t)(m0 + 16 * w + lc * 4 + r) * DMODEL + n0 + nt * 16 + lr] =
                acc[nt][r] + b;
    }
}

extern "C" void kernel_launch(void* const* d_in, const int* in_sizes, int n_in,
                              void* d_out, int out_size, void* d_ws, size_t ws_size,
                              hipStream_t stream) {
    const float* x  = (const float*)d_in[0];
    const float* Wq = (const float*)d_in[1];
    const float* Wk = (const float*)d_in[2];
    const float* Wv = (const float*)d_in[3];
    const float* Wo = (const float*)d_in[4];
    const float* bo = (const float*)d_in[5];
    float* out = (float*)d_out;

    // Workspace layout (bytes). Opart overlays xh/WTq/WTk/WTv (disjoint
    // lifetimes: xh/WT die at qkv_gemm16 end; Opart born in attn_fwd).
    char* base = (char*)d_ws;
    f16*   Opart = (f16*)base;                   // 2*8*4096*64*2 = 8,388,608
    f16*   xh    = (f16*)base;                   // 5,242,880
    f16*   WTq   = xh + (size_t)NSEQ * DMODEL;
    f16*   WTk   = WTq + (size_t)INNER * DMODEL;
    f16*   WTv   = WTk + (size_t)INNER * DMODEL; // ends 7,208,960 < 8,388,608
    float* Ml    = (float*)(base + 8388608);     // 2*8*4096*2*4 = 524,288
    f16*   WoT   = (f16*)(base + 8912896);       // 655,360
    f16*   q16   = (f16*)(base + 9568256);       // 4,194,304
    f16*   k16   = q16 + (size_t)NHEAD * NSEQ * DHEAD;
    f16*   vT16  = k16 + (size_t)NHEAD * NSEQ * DHEAD;  // ends 22,151,168 B

    cvt_x<<<NSEQ * DMODEL / (256 * 8), 256, 0, stream>>>(x, xh);
    transpose_cvt3<<<dim3(INNER / 64, DMODEL / 64, 3), 256, 0, stream>>>(
        Wq, Wk, Wv, WTq, WTk, WTv);
    transpose_cvt<<<dim3(DMODEL / 64, INNER / 64), 256, 0, stream>>>(
        Wo, WoT, INNER, DMODEL);

    qkv_gemm16<<<dim3(NHEAD, NSEQ / 64, 3), 256, 0, stream>>>(
        xh, WTq, WTk, WTv, q16, k16, vT16);
    attn_fwd<<<dim3(NSEQ / 128, NHEAD, KVSPLIT), 256, 0, stream>>>(
        q16, k16, vT16, Opart, Ml);
    out_gemm16<<<dim3(DMODEL / 64, NSEQ / 64), 256, 0, stream>>>(
        Opart, Ml, WoT, bo, out);
}